// Round 5
// baseline (4311.390 us; speedup 1.0000x reference)
//
#include <hip/hip_runtime.h>
#include <cstdint>
#include <cstddef>

#define T_SEQ 1024
#define BATCH 64
#define DIM   256
#define HID   256
#define NG    (4*HID)   // 1024 gate columns, jp = 4r + g, g in {f,i,g~,o}

typedef _Float16 h2v __attribute__((ext_vector_type(2)));
union U16 { uint4 u; h2v h[4]; };
union PU64 { float2 f2; unsigned long long u; };

__device__ __forceinline__ float sigm_f(float x) {
    return 1.0f / (1.0f + __expf(-x));
}
__device__ __forceinline__ float tanh_f(float x) {
    x = fminf(fmaxf(x, -15.0f), 15.0f);   // avoid inf/inf
    float e = __expf(2.0f * x);
    return (e - 1.0f) / (e + 1.0f);
}

// DPP quad_perm [1,0,3,2] = swap adjacent lane pairs (xor-1), VALU pipe
#define QP_XOR1(x) __int_as_float(__builtin_amdgcn_mov_dpp(__float_as_int(x), 0xB1, 0xf, 0xf, true))

// ---------------- phase 0: repack weights, zero state -------------------------
// wx4[k*1024 + jp] = W_g[r][k]            (x part, fp32; jp = 4r+g)
// whB (h part, fp16), k-HALF split layout for the 2-WG recurrence:
//   half = k>>7, kk = k&127, c = kk>>3 (chunk 0..15), e = k&7
//   col jp -> tcol = jp>>1, s = jp&1
//   whB[(((half*16 + c)*2 + s)*512 + tcol)*8 + e] = fp16(W_g[r][256+k])
// bias4[jp] = b_g[r]; zero h/c state and exchange flags.
__global__ void pack_kernel(const float* __restrict__ Wf, const float* __restrict__ bf,
                            const float* __restrict__ Wi, const float* __restrict__ bi,
                            const float* __restrict__ Wg, const float* __restrict__ bg,
                            const float* __restrict__ Wo, const float* __restrict__ bo,
                            float* __restrict__ wx4, _Float16* __restrict__ whB,
                            float* __restrict__ bias4,
                            float* __restrict__ hstate, float* __restrict__ cstate,
                            unsigned* __restrict__ flags) {
    int k = blockIdx.x;          // 0..255
    int j = threadIdx.x;         // 0..1023
    int r = j & 255, g = j >> 8;
    const float* W  = (g == 0) ? Wf : (g == 1) ? Wi : (g == 2) ? Wg : Wo;
    const float* bb = (g == 0) ? bf : (g == 1) ? bi : (g == 2) ? bg : bo;
    int jp = r * 4 + g;
    wx4[(size_t)k * 1024 + jp] = W[(size_t)r * 512 + k];
    {
        int half = k >> 7, kk = k & 127;
        int c = kk >> 3, e = k & 7;
        int tcol = jp >> 1, s = jp & 1;
        whB[(((size_t)((half * 16 + c) * 2 + s)) * 512 + tcol) * 8 + e] =
            (_Float16)W[(size_t)r * 512 + 256 + k];
    }
    if (k == 0) bias4[jp] = bb[r];
    if (k < 64 && g == 0) hstate[k * 256 + r] = 0.0f;
    if (k < 64 && g == 1) cstate[k * 256 + r] = 0.0f;
    if (k == 1 && j < 512) flags[j] = 0;   // 64 b x 2 half x 4 waves
}

// ---------------- phase 1: Xproj ----------------------------------------------
// xp[row][jp] with jp = tid*4+g contiguous (float4 per r) -> the recurrence
// reads ONE float2 (cols 2t, 2t+1) per step per keep-thread.
__global__ __launch_bounds__(256) void xproj_kernel(
        const float* __restrict__ X, const float* __restrict__ wx4,
        const float* __restrict__ bias4, float4* __restrict__ xp) {
    __shared__ __align__(16) float xl[256 * 20];   // [k][row] padded
    int tid = threadIdx.x;
    int R0 = blockIdx.x * 16;
    #pragma unroll
    for (int i = 0; i < 16; ++i)
        xl[tid * 20 + i] = X[(size_t)(R0 + i) * DIM + tid];
    __syncthreads();

    float4 bv = ((const float4*)bias4)[tid];
    float acc[16][4];
    #pragma unroll
    for (int i = 0; i < 16; ++i) {
        acc[i][0] = bv.x; acc[i][1] = bv.y; acc[i][2] = bv.z; acc[i][3] = bv.w;
    }
    const float4* __restrict__ wp = (const float4*)wx4 + tid;
    #pragma unroll 2
    for (int k = 0; k < 256; ++k) {
        float4 w  = wp[k << 8];
        float4 xa = *(const float4*)&xl[k * 20 + 0];
        float4 xb = *(const float4*)&xl[k * 20 + 4];
        float4 xc = *(const float4*)&xl[k * 20 + 8];
        float4 xd = *(const float4*)&xl[k * 20 + 12];
        float xr[16] = {xa.x, xa.y, xa.z, xa.w, xb.x, xb.y, xb.z, xb.w,
                        xc.x, xc.y, xc.z, xc.w, xd.x, xd.y, xd.z, xd.w};
        #pragma unroll
        for (int i = 0; i < 16; ++i) {
            acc[i][0] = fmaf(xr[i], w.x, acc[i][0]);
            acc[i][1] = fmaf(xr[i], w.y, acc[i][1]);
            acc[i][2] = fmaf(xr[i], w.z, acc[i][2]);
            acc[i][3] = fmaf(xr[i], w.w, acc[i][3]);
        }
    }
    #pragma unroll
    for (int i = 0; i < 16; ++i) {
        float4 v;
        v.x = acc[i][0]; v.y = acc[i][1]; v.z = acc[i][2]; v.w = acc[i][3];
        xp[(size_t)(R0 + i) * 256 + tid] = v;
    }
}

// ---------------- phase 2: recurrence, TWO WGs (k-halves) per batch ----------
// WG (b, half) computes gate partials over k in [128*half, 128*half+128) for
// ALL 1024 cols. Keep-threads (cols on own side) receive the partner's
// partials, finish the gates, and produce h rows [128*half, 128*half+128) --
// exactly the h-slice this WG's next matvec needs, so h never crosses WGs.
// Exchange: 2 KB of partials/step via LLC (relaxed agent atomics); per-wave
// flags (store -> vmcnt(0) -> lane-0 flag), parity-double-buffered pbuf.
// Weights/WG: 256 KB = 8 chunks LDS (128 KB) + 8 chunks in 64 arch VGPRs
// (slab now fits the 128-reg arch file: NO v_accvgpr move tax).
__global__ __launch_bounds__(512, 2) void lstm_step_kernel(
        const float* __restrict__ xp, const _Float16* __restrict__ whB,
        float* __restrict__ hstate, float* __restrict__ cstate,
        float* __restrict__ out, unsigned* __restrict__ flags,
        float2* __restrict__ pbuf, int t0, int Tc) {
    __shared__ __align__(16) _Float16 wl[8 * 2 * 512 * 8];   // 128 KB: chunks 0..7
    __shared__ __align__(16) _Float16 hl[2][128];            // own h-half, dbuf
    int t = threadIdx.x;
    // XCD-colocate the (b,0)/(b,1) pair: 16 consecutive-slot WGs per XCD
    int orig = blockIdx.x;
    int xcd = orig & 7, idx = orig >> 3;       // idx 0..15 within XCD
    int b = xcd * 8 + (idx >> 1);
    int half = idx & 1;

    // stage chunks 0..7 of this half into LDS (8192 uint4 over 512 thr)
    const uint4* wsrc = (const uint4*)whB + (size_t)half * 16384;
    {
        uint4* dst = (uint4*)wl;
        #pragma unroll
        for (int i = 0; i < 16; ++i)
            dst[i * 512 + t] = wsrc[i * 512 + t];
    }
    // register slab: chunks 8..15 for cols 2t (s=0) and 2t+1 (s=1)
    uint4 wr0[8], wr1[8];
    #pragma unroll
    for (int i = 0; i < 8; ++i) {
        wr0[i] = wsrc[(size_t)((8 + i) * 2 + 0) * 512 + t];
        wr1[i] = wsrc[(size_t)((8 + i) * 2 + 1) * 512 + t];
    }
    int iskeep = (half == 0) ? (t < 256) : (t >= 256);   // wave-uniform
    int podd = t & 1;
    float creg = 0.0f;
    if (iskeep) creg = cstate[b * HID + (t >> 1)];
    if (t < 128) hl[0][t] = (_Float16)hstate[b * HID + half * 128 + t];
    float sm = podd ? 2.0f : 1.0f;
    float aa = sm, bbc = podd ? -1.0f : 0.0f;
    __syncthreads();

    const float2* __restrict__ xpf2 = (const float2*)xp;
    float2 xa2 = {0.0f, 0.0f};
    if (iskeep) xa2 = xpf2[(size_t)b * 512 + t];
    int w4 = (t >> 6) & 3;
    unsigned* flprod = &flags[(b * 2 + half) * 4 + w4];
    unsigned* flcons = &flags[(b * 2 + (1 - half)) * 4 + w4];
    int cur = 0;
    for (int tt = 0; tt < Tc; ++tt) {
        // prefetch next step's xp (keep threads only)
        float2 xn2 = xa2;
        if (iskeep) {
            int tn = (tt + 1 < Tc) ? tt + 1 : tt;
            xn2 = xpf2[((size_t)tn * BATCH + b) * 512 + t];
        }
        float s0a = 0.f, s0b = 0.f, s1a = 0.f, s1b = 0.f;
        const _Float16* hb = hl[cur];
        // LDS chunks 0..7
        #pragma unroll
        for (int c = 0; c < 8; ++c) {
            U16 h, w0, w1;
            h.u  = *(const uint4*)&hb[c * 8];                       // broadcast
            w0.u = *(const uint4*)&wl[((size_t)(c * 2 + 0) * 512 + t) * 8];
            w1.u = *(const uint4*)&wl[((size_t)(c * 2 + 1) * 512 + t) * 8];
            s0a = __builtin_amdgcn_fdot2(w0.h[0], h.h[0], s0a, false);
            s0b = __builtin_amdgcn_fdot2(w0.h[1], h.h[1], s0b, false);
            s0a = __builtin_amdgcn_fdot2(w0.h[2], h.h[2], s0a, false);
            s0b = __builtin_amdgcn_fdot2(w0.h[3], h.h[3], s0b, false);
            s1a = __builtin_amdgcn_fdot2(w1.h[0], h.h[0], s1a, false);
            s1b = __builtin_amdgcn_fdot2(w1.h[1], h.h[1], s1b, false);
            s1a = __builtin_amdgcn_fdot2(w1.h[2], h.h[2], s1a, false);
            s1b = __builtin_amdgcn_fdot2(w1.h[3], h.h[3], s1b, false);
        }
        // register chunks 8..15
        #pragma unroll
        for (int i = 0; i < 8; ++i) {
            U16 h, w0, w1;
            h.u  = *(const uint4*)&hb[(8 + i) * 8];                 // broadcast
            w0.u = wr0[i];
            w1.u = wr1[i];
            s0a = __builtin_amdgcn_fdot2(w0.h[0], h.h[0], s0a, false);
            s0b = __builtin_amdgcn_fdot2(w0.h[1], h.h[1], s0b, false);
            s0a = __builtin_amdgcn_fdot2(w0.h[2], h.h[2], s0a, false);
            s0b = __builtin_amdgcn_fdot2(w0.h[3], h.h[3], s0b, false);
            s1a = __builtin_amdgcn_fdot2(w1.h[0], h.h[0], s1a, false);
            s1b = __builtin_amdgcn_fdot2(w1.h[1], h.h[1], s1b, false);
            s1a = __builtin_amdgcn_fdot2(w1.h[2], h.h[2], s1a, false);
            s1b = __builtin_amdgcn_fdot2(w1.h[3], h.h[3], s1b, false);
        }
        int parity = tt & 1;
        if (!iskeep) {
            // export: partials -> LLC, then per-wave flag (vmcnt(0) orders
            // the whole wave's data stores before lane 0's flag store)
            PU64 p; p.f2.x = s0a + s0b; p.f2.y = s1a + s1b;
            __hip_atomic_store(
                (unsigned long long*)&pbuf[((size_t)(b * 2 + half) * 2 + parity) * 512 + t],
                p.u, __ATOMIC_RELAXED, __HIP_MEMORY_SCOPE_AGENT);
            asm volatile("s_waitcnt vmcnt(0)" ::: "memory");
            if ((t & 63) == 0)
                __hip_atomic_store(flprod, (unsigned)(t0 + tt + 1),
                                   __ATOMIC_RELAXED, __HIP_MEMORY_SCOPE_AGENT);
        } else {
            // keep: wait partner wave's partials, finish gates, update state
            unsigned want = (unsigned)(t0 + tt + 1);
            while (__hip_atomic_load(flcons, __ATOMIC_RELAXED,
                                     __HIP_MEMORY_SCOPE_AGENT) < want) {}
            PU64 p;
            p.u = __hip_atomic_load(
                (const unsigned long long*)&pbuf[((size_t)(b * 2 + (1 - half)) * 2 + parity) * 512 + t],
                __ATOMIC_RELAXED, __HIP_MEMORY_SCOPE_AGENT);
            float a0 = xa2.x + s0a + s0b + p.f2.x;   // col 2t   (even: f | odd: g~)
            float a1 = xa2.y + s1a + s1b + p.f2.y;   // col 2t+1 (even: i | odd: o)
            float vA = fmaf(aa, sigm_f(sm * a0), bbc);
            float vB = sigm_f(a1);
            float eA = QP_XOR1(vA);
            float eB = QP_XOR1(vB);
            float f  = podd ? eA : vA;
            float ii = podd ? eB : vB;
            float gg = podd ? vA : eA;
            float o  = podd ? vB : eB;
            float c  = fmaf(f, creg, ii * gg);
            creg = c;
            float h  = o * tanh_f(c);
            if (!podd) hl[cur ^ 1][(t >> 1) & 127] = (_Float16)h;
        }
        __syncthreads();
        // coalesced out-store of own h-half, post-barrier
        if (t < 128)
            out[((size_t)(t0 + tt) * BATCH + b) * HID + half * 128 + t] =
                (float)hl[cur ^ 1][t];
        xa2 = xn2;
        cur ^= 1;
    }
    if (t < 128) hstate[b * HID + half * 128 + t] = (float)hl[cur][t];
    if (iskeep && !podd) cstate[b * HID + (t >> 1)] = creg;
}

// ---------------- tail: final hx, cx ------------------------------------------
__global__ void tail_kernel(const float* __restrict__ hstate,
                            const float* __restrict__ cstate, float* __restrict__ out) {
    int b = blockIdx.x, r = threadIdx.x;
    size_t base = (size_t)T_SEQ * BATCH * HID;
    out[base + b * HID + r] = hstate[b * HID + r];
    out[base + (size_t)BATCH * HID + b * HID + r] = cstate[b * HID + r];
}

extern "C" void kernel_launch(void* const* d_in, const int* in_sizes, int n_in,
                              void* d_out, int out_size, void* d_ws, size_t ws_size,
                              hipStream_t stream) {
    (void)in_sizes; (void)n_in; (void)out_size;
    const float* X  = (const float*)d_in[0];
    const float* Wf = (const float*)d_in[1];
    const float* bf = (const float*)d_in[2];
    const float* Wi = (const float*)d_in[3];
    const float* bi = (const float*)d_in[4];
    const float* Wg = (const float*)d_in[5];
    const float* bg = (const float*)d_in[6];
    const float* Wo = (const float*)d_in[7];
    const float* bo = (const float*)d_in[8];
    float* out = (float*)d_out;
    char*  ws  = (char*)d_ws;

    const size_t MB = 1 << 20, KB = 1 << 10;
    float*    wx4    = (float*)(ws);                          // 1 MB
    _Float16* whB    = (_Float16*)(ws + MB);                  // 512 KB
    float*    bias4  = (float*)(ws + MB + 512 * KB);          // 4 KB
    float*    hstate = (float*)(ws + MB + 576 * KB);          // 64 KB
    float*    cstate = (float*)(ws + MB + 640 * KB);          // 64 KB
    unsigned* flags  = (unsigned*)(ws + MB + 704 * KB);       // 2 KB
    float2*   pbuf   = (float2*)(ws + MB + 768 * KB);         // 1 MB
    float4*   xproj  = (float4*)(ws + 3 * MB);

    size_t fixed = 3 * MB;
    int Tc = 1024;
    while (Tc > 16 && fixed + (size_t)Tc * BATCH * NG * 4 > ws_size) Tc >>= 1;

    pack_kernel<<<256, 1024, 0, stream>>>(Wf, bf, Wi, bi, Wg, bg, Wo, bo,
                                          wx4, whB, bias4, hstate, cstate, flags);
    for (int t0 = 0; t0 < T_SEQ; t0 += Tc) {
        xproj_kernel<<<Tc * BATCH / 16, 256, 0, stream>>>(
            X + (size_t)t0 * BATCH * DIM, wx4, bias4, xproj);
        lstm_step_kernel<<<128, 512, 0, stream>>>(
            (const float*)xproj, whB, hstate, cstate, out, flags, pbuf, t0, Tc);
    }
    tail_kernel<<<BATCH, HID, 0, stream>>>(hstate, cstate, out);
}

// Round 7
// 2300.121 us; speedup vs baseline: 1.8744x; 1.8744x over previous
//
#include <hip/hip_runtime.h>
#include <cstdint>
#include <cstddef>

#define T_SEQ 1024
#define BATCH 64
#define DIM   256
#define HID   256
#define NG    (4*HID)   // 1024 gate columns, jp = 4r + g, g in {f,i,g~,o}

typedef _Float16 h2v __attribute__((ext_vector_type(2)));
union U16 { uint4 u; h2v h[4]; };
union HV  { uint4 u; int i[4]; };
union SH  { int i; h2v h; };

__device__ __forceinline__ float sigm_f(float x) {
    return 1.0f / (1.0f + __expf(-x));
}
__device__ __forceinline__ float tanh_f(float x) {
    x = fminf(fmaxf(x, -15.0f), 15.0f);   // avoid inf/inf
    float e = __expf(2.0f * x);
    return (e - 1.0f) / (e + 1.0f);
}

// DPP quad_perm [1,0,3,2] = swap adjacent lane pairs (xor-1), VALU pipe
#define QP_XOR1(x) __int_as_float(__builtin_amdgcn_mov_dpp(__float_as_int(x), 0xB1, 0xf, 0xf, true))

// ---------------- phase 0: repack weights, zero state -------------------------
// wx4[k*1024 + jp] = W_g[r][k]            (x part, fp32; jp = 4r+g)
// whB (h part, fp16, k-packs of 8), column-pair layout for the recurrence:
//   col jp -> thread t = jp>>1, slot s = jp&1; chunk k8 = k>>3, elem e = k&7
//   whB[((k8*2 + s)*512 + t)*8 + e] = fp16(W_g[r][256+k])
// bias4[jp] = b_g[r]
__global__ void pack_kernel(const float* __restrict__ Wf, const float* __restrict__ bf,
                            const float* __restrict__ Wi, const float* __restrict__ bi,
                            const float* __restrict__ Wg, const float* __restrict__ bg,
                            const float* __restrict__ Wo, const float* __restrict__ bo,
                            float* __restrict__ wx4, _Float16* __restrict__ whB,
                            float* __restrict__ bias4,
                            float* __restrict__ hstate, float* __restrict__ cstate) {
    int k = blockIdx.x;          // 0..255
    int j = threadIdx.x;         // 0..1023
    int r = j & 255, g = j >> 8;
    const float* W  = (g == 0) ? Wf : (g == 1) ? Wi : (g == 2) ? Wg : Wo;
    const float* bb = (g == 0) ? bf : (g == 1) ? bi : (g == 2) ? bg : bo;
    int jp = r * 4 + g;
    wx4[(size_t)k * 1024 + jp] = W[(size_t)r * 512 + k];
    {
        int k8 = k >> 3, e = k & 7, t = jp >> 1, s = jp & 1;
        whB[(((size_t)(k8 * 2 + s)) * 512 + t) * 8 + e] = (_Float16)W[(size_t)r * 512 + 256 + k];
    }
    if (k == 0) bias4[jp] = bb[r];
    if (k < 64 && g == 0) hstate[k * 256 + r] = 0.0f;
    if (k < 64 && g == 1) cstate[k * 256 + r] = 0.0f;
}

// ---------------- phase 1: Xproj ----------------------------------------------
// xp[row][jp] with jp = tid*4+g contiguous (float4 per r) -> the recurrence
// reads ONE float2 (cols 2t, 2t+1) per step per thread.
__global__ __launch_bounds__(256) void xproj_kernel(
        const float* __restrict__ X, const float* __restrict__ wx4,
        const float* __restrict__ bias4, float4* __restrict__ xp) {
    __shared__ __align__(16) float xl[256 * 20];   // [k][row] padded
    int tid = threadIdx.x;
    int R0 = blockIdx.x * 16;
    #pragma unroll
    for (int i = 0; i < 16; ++i)
        xl[tid * 20 + i] = X[(size_t)(R0 + i) * DIM + tid];
    __syncthreads();

    float4 bv = ((const float4*)bias4)[tid];
    float acc[16][4];
    #pragma unroll
    for (int i = 0; i < 16; ++i) {
        acc[i][0] = bv.x; acc[i][1] = bv.y; acc[i][2] = bv.z; acc[i][3] = bv.w;
    }
    const float4* __restrict__ wp = (const float4*)wx4 + tid;
    #pragma unroll 2
    for (int k = 0; k < 256; ++k) {
        float4 w  = wp[k << 8];
        float4 xa = *(const float4*)&xl[k * 20 + 0];
        float4 xb = *(const float4*)&xl[k * 20 + 4];
        float4 xc = *(const float4*)&xl[k * 20 + 8];
        float4 xd = *(const float4*)&xl[k * 20 + 12];
        float xr[16] = {xa.x, xa.y, xa.z, xa.w, xb.x, xb.y, xb.z, xb.w,
                        xc.x, xc.y, xc.z, xc.w, xd.x, xd.y, xd.z, xd.w};
        #pragma unroll
        for (int i = 0; i < 16; ++i) {
            acc[i][0] = fmaf(xr[i], w.x, acc[i][0]);
            acc[i][1] = fmaf(xr[i], w.y, acc[i][1]);
            acc[i][2] = fmaf(xr[i], w.z, acc[i][2]);
            acc[i][3] = fmaf(xr[i], w.w, acc[i][3]);
        }
    }
    #pragma unroll
    for (int i = 0; i < 16; ++i) {
        float4 v;
        v.x = acc[i][0]; v.y = acc[i][1]; v.z = acc[i][2]; v.w = acc[i][3];
        xp[(size_t)(R0 + i) * 256 + tid] = v;
    }
}

// ---------------- phase 2: sequential recurrence, 1 WG per batch element -----
// 512 threads (8 waves, 2/SIMD). Thread t owns cols 2t,2t+1 (jp=4r+g); the
// lane pair holds all 4 gates -> DPP exchange, c pair-replicated, ONE barrier
// per step, out-store post-barrier (as round-4 winner).
// h is broadcast via READLANE, not LDS: per wave per step ONE ds_read_b128
// loads all 256 h halfs (lane l&31 holds k8-chunk l&31); each chunk's 4
// dwords go readlane->SGPR and feed v_dot2 as the SGPR operand.
// LDS traffic/CU/step: 393KB -> ~140KB (h-broadcast redundancy eliminated).
__global__ __launch_bounds__(512, 2) void lstm_step_kernel(
        const float* __restrict__ xp, const _Float16* __restrict__ whB,
        float* __restrict__ hstate, float* __restrict__ cstate,
        float* __restrict__ out, int t0, int Tc) {
    __shared__ __align__(16) _Float16 wl[8 * 2 * 512 * 8];   // 128 KB: k8 = 0..7
    __shared__ __align__(16) _Float16 hl[2][HID];            // double-buffered h
    int t = threadIdx.x, b = blockIdx.x;
    int lane = t & 63;

    // stage k8 = 0..7 into LDS (8192 uint4 over 512 threads = 16 each)
    {
        const uint4* src = (const uint4*)whB;
        uint4* dst = (uint4*)wl;
        #pragma unroll
        for (int i = 0; i < 16; ++i)
            dst[i * 512 + t] = src[i * 512 + t];
    }
    // register slab: k8 = 8..31 for cols 2t (slot 0) and 2t+1 (slot 1)
    uint4 wr0[24], wr1[24];
    {
        const uint4* src = (const uint4*)whB;
        #pragma unroll
        for (int i = 0; i < 24; ++i) {
            wr0[i] = src[(size_t)((8 + i) * 2 + 0) * 512 + t];
            wr1[i] = src[(size_t)((8 + i) * 2 + 1) * 512 + t];
        }
    }
    int podd = t & 1;
    float creg = cstate[b * HID + (t >> 1)];       // pair-replicated
    if (t < HID) hl[0][t] = (_Float16)hstate[b * HID + t];
    // branchless gate-A activation: even: sigm(x); odd: tanh(x)=2*sigm(2x)-1
    float sm = podd ? 2.0f : 1.0f;
    float aa = sm, bbc = podd ? -1.0f : 0.0f;
    __syncthreads();

    const float2* __restrict__ xpf2 = (const float2*)xp;
    float2 xa2 = xpf2[(size_t)b * 512 + t];
    int cur = 0;
    for (int tt = 0; tt < Tc; ++tt) {
        // prefetch next step's xp early (hides latency under the dot chain)
        int tn = (tt + 1 < Tc) ? tt + 1 : tt;
        float2 xn2 = xpf2[((size_t)tn * BATCH + b) * 512 + t];

        // cooperative h load: lane l&31 holds k8-chunk l&31 (8 halfs)
        HV hv;
        hv.u = *(const uint4*)&hl[cur][(lane & 31) * 8];

        float s0a = 0.f, s0b = 0.f, s1a = 0.f, s1b = 0.f;
        // LDS-weight part: k8 = 0..7 (h via readlane -> SGPR operand)
        #pragma unroll
        for (int c = 0; c < 8; ++c) {
            U16 w0, w1;
            w0.u = *(const uint4*)&wl[((size_t)(c * 2 + 0) * 512 + t) * 8];
            w1.u = *(const uint4*)&wl[((size_t)(c * 2 + 1) * 512 + t) * 8];
            SH h0, h1, h2, h3;
            h0.i = __builtin_amdgcn_readlane(hv.i[0], c);
            h1.i = __builtin_amdgcn_readlane(hv.i[1], c);
            h2.i = __builtin_amdgcn_readlane(hv.i[2], c);
            h3.i = __builtin_amdgcn_readlane(hv.i[3], c);
            s0a = __builtin_amdgcn_fdot2(w0.h[0], h0.h, s0a, false);
            s0b = __builtin_amdgcn_fdot2(w0.h[1], h1.h, s0b, false);
            s0a = __builtin_amdgcn_fdot2(w0.h[2], h2.h, s0a, false);
            s0b = __builtin_amdgcn_fdot2(w0.h[3], h3.h, s0b, false);
            s1a = __builtin_amdgcn_fdot2(w1.h[0], h0.h, s1a, false);
            s1b = __builtin_amdgcn_fdot2(w1.h[1], h1.h, s1b, false);
            s1a = __builtin_amdgcn_fdot2(w1.h[2], h2.h, s1a, false);
            s1b = __builtin_amdgcn_fdot2(w1.h[3], h3.h, s1b, false);
        }
        // register-weight part: k8 = 8..31
        #pragma unroll
        for (int i = 0; i < 24; ++i) {
            U16 w0, w1;
            w0.u = wr0[i];
            w1.u = wr1[i];
            SH h0, h1, h2, h3;
            h0.i = __builtin_amdgcn_readlane(hv.i[0], 8 + i);
            h1.i = __builtin_amdgcn_readlane(hv.i[1], 8 + i);
            h2.i = __builtin_amdgcn_readlane(hv.i[2], 8 + i);
            h3.i = __builtin_amdgcn_readlane(hv.i[3], 8 + i);
            s0a = __builtin_amdgcn_fdot2(w0.h[0], h0.h, s0a, false);
            s0b = __builtin_amdgcn_fdot2(w0.h[1], h1.h, s0b, false);
            s0a = __builtin_amdgcn_fdot2(w0.h[2], h2.h, s0a, false);
            s0b = __builtin_amdgcn_fdot2(w0.h[3], h3.h, s0b, false);
            s1a = __builtin_amdgcn_fdot2(w1.h[0], h0.h, s1a, false);
            s1b = __builtin_amdgcn_fdot2(w1.h[1], h1.h, s1b, false);
            s1a = __builtin_amdgcn_fdot2(w1.h[2], h2.h, s1a, false);
            s1b = __builtin_amdgcn_fdot2(w1.h[3], h3.h, s1b, false);
        }
        float a0 = xa2.x + s0a + s0b;      // col 2t   (even: f | odd: g~)
        float a1 = xa2.y + s1a + s1b;      // col 2t+1 (even: i | odd: o)
        float vA = fmaf(aa, sigm_f(sm * a0), bbc);
        float vB = sigm_f(a1);
        float eA = QP_XOR1(vA);            // partner's A value
        float eB = QP_XOR1(vB);            // partner's B value
        float f  = podd ? eA : vA;
        float ii = podd ? eB : vB;
        float gg = podd ? vA : eA;
        float o  = podd ? vB : eB;
        float c  = fmaf(f, creg, ii * gg);
        creg = c;
        float h  = o * tanh_f(c);
        if (!podd) hl[cur ^ 1][t >> 1] = (_Float16)h;
        __syncthreads();
        // coalesced out-store post-barrier (drains at next step's barrier)
        if (t < HID)
            out[((size_t)(t0 + tt) * BATCH + b) * HID + t] = (float)hl[cur ^ 1][t];
        xa2 = xn2;
        cur ^= 1;
    }
    if (t < HID) hstate[b * HID + t] = (float)hl[cur][t];
    if (!podd)   cstate[b * HID + (t >> 1)] = creg;
}

// ---------------- tail: final hx, cx ------------------------------------------
__global__ void tail_kernel(const float* __restrict__ hstate,
                            const float* __restrict__ cstate, float* __restrict__ out) {
    int b = blockIdx.x, r = threadIdx.x;
    size_t base = (size_t)T_SEQ * BATCH * HID;
    out[base + b * HID + r] = hstate[b * HID + r];
    out[base + (size_t)BATCH * HID + b * HID + r] = cstate[b * HID + r];
}

extern "C" void kernel_launch(void* const* d_in, const int* in_sizes, int n_in,
                              void* d_out, int out_size, void* d_ws, size_t ws_size,
                              hipStream_t stream) {
    (void)in_sizes; (void)n_in; (void)out_size;
    const float* X  = (const float*)d_in[0];
    const float* Wf = (const float*)d_in[1];
    const float* bf = (const float*)d_in[2];
    const float* Wi = (const float*)d_in[3];
    const float* bi = (const float*)d_in[4];
    const float* Wg = (const float*)d_in[5];
    const float* bg = (const float*)d_in[6];
    const float* Wo = (const float*)d_in[7];
    const float* bo = (const float*)d_in[8];
    float* out = (float*)d_out;
    char*  ws  = (char*)d_ws;

    const size_t MB = 1 << 20, KB = 1 << 10;
    float*    wx4    = (float*)(ws);                          // 1 MB
    _Float16* whB    = (_Float16*)(ws + MB);                  // 512 KB
    float*    bias4  = (float*)(ws + MB + 512 * KB);          // 4 KB
    float*    hstate = (float*)(ws + MB + 576 * KB);          // 64 KB
    float*    cstate = (float*)(ws + MB + 640 * KB);          // 64 KB
    float4*   xproj  = (float4*)(ws + 2 * MB);

    size_t fixed = 2 * MB;
    int Tc = 1024;
    while (Tc > 16 && fixed + (size_t)Tc * BATCH * NG * 4 > ws_size) Tc >>= 1;

    pack_kernel<<<256, 1024, 0, stream>>>(Wf, bf, Wi, bi, Wg, bg, Wo, bo,
                                          wx4, whB, bias4, hstate, cstate);
    for (int t0 = 0; t0 < T_SEQ; t0 += Tc) {
        xproj_kernel<<<Tc * BATCH / 16, 256, 0, stream>>>(
            X + (size_t)t0 * BATCH * DIM, wx4, bias4, xproj);
        lstm_step_kernel<<<BATCH, 512, 0, stream>>>(
            (const float*)xproj, whB, hstate, cstate, out, t0, Tc);
    }
    tail_kernel<<<BATCH, HID, 0, stream>>>(hstate, cstate, out);
}